// Round 1
// baseline (89.589 us; speedup 1.0000x reference)
//
#include <hip/hip_runtime.h>

// ---------------------------------------------------------------------------
// GlimpseNetwork forward, fp32. Round 9:
//  * glimpse_conv: 320-thread blocks, single-pass conv2 (t -> (py,oc)),
//    conv2 weights double-buffered in LDS (8-ch chunks, staged during conv1
//    and overlapped with compute) -> removes L2-latency chain in conv2.
//  * fc3/fc4 weights repacked to [k4][384][4] -> lane-coalesced streaming
//    reads in fc_tail (was per-lane row-major walk thrashing L1).
// Pipeline:
//   repack (672 blk) : c2w->w2t[r][64oc]; c1w->w1t; f3w->w3t; f4w->w4t
//   glimpse_conv(512x320): foveate->in_s(LDS), conv1->h1_s, conv2(LDS w)->h2
//   fc1_partial(64x8): K-split GEMM -> partial
//   fc_tail (256)    : reduce+ReLU->phi_out, fc2, fc3/fc4 -> g_t
//
// d_out layout (floats): phi_out[512*256] | g_t[512*384] | bboxes[512*12*4]
// ws (floats): h2[0,819200) part[819200,1867776) w2t[1867776,1886208)
//              w1t[1886208,1892352) w3t[1892352,1990656) w4t[1990656,2039808)
// ---------------------------------------------------------------------------

#define PHI_OUT_OFF 0
#define GT_OFF      131072
#define BBOX_OFF    327680

#define WS_H2    0
#define WS_PART  819200
#define WS_W2T   1867776
#define WS_W1T   1886208
#define WS_W3T   1892352
#define WS_W4T   1990656

// ---- Kernel 0: weight repacks --------------------------------------------
__global__ __launch_bounds__(256) void repack_kernel(
    const float* __restrict__ c2w,   // [64,32,3,3]
    const float* __restrict__ c1w,   // [32,12,4,4]
    const float* __restrict__ f3w,   // [384,256]
    const float* __restrict__ f4w,   // [384,128]
    float* __restrict__ w2t,         // [288,64]
    float* __restrict__ w1t,         // [48,4,32]
    float* __restrict__ w3t,         // [64,384,4]
    float* __restrict__ w4t)         // [32,384,4]
{
    int idx = blockIdx.x * 256 + threadIdx.x;
    if (idx < 18432) {                         // conv2: [oc][r] -> [r][64oc]
        int oc = idx / 288, r = idx % 288;
        w2t[r * 64 + oc] = c2w[idx];
    } else if (idx < 24576) {                  // conv1 -> [(ch*4+ky)][kx][32oc]
        int g1 = idx - 18432;
        int oc = g1 / 192, rem = g1 % 192;
        int ch = rem / 16, kk = rem % 16, ky = kk / 4, kx = kk % 4;
        w1t[(ch * 4 + ky) * 128 + kx * 32 + oc] = c1w[g1];
    } else if (idx < 122880) {                 // fc3: [ch][k] -> [k4][384ch][4]
        int i = idx - 24576;
        int ch = i >> 8, k = i & 255;
        w3t[((k >> 2) * 384 + ch) * 4 + (k & 3)] = f3w[i];
    } else if (idx < 172032) {                 // fc4: [ch][k] -> [k4][384ch][4]
        int i = idx - 122880;
        int ch = i >> 7, k = i & 127;
        w4t[((k >> 2) * 384 + ch) * 4 + (k & 3)] = f4w[i];
    }
}

// ---- Kernel 1: fused foveate + conv1 + conv2, one block per image ---------
// 512 blocks, 320 threads. LDS: w2s 36.9 KB (buf1 aliases in_s) + h1_s 7.2 KB.
__global__ __launch_bounds__(320) void glimpse_conv_kernel(
    const float* __restrict__ x,     // [512,1,256,256]
    const float* __restrict__ l,     // [512,4,2]
    const float* __restrict__ w1t,   // [48,4,32]
    const float* __restrict__ c1b,   // [32]
    const float* __restrict__ w2t,   // [288,64]
    const float* __restrict__ c2b,   // [64]
    float* __restrict__ h2,          // [512,1600]
    float* __restrict__ bbox)        // [512,12,4]
{
    __shared__ __align__(16) float w2s[2][4608];  // conv2 weight double-buffer
    __shared__ __align__(16) float h1_s[32 * 7 * 8];
    float* in_s = w2s[1];                 // foveated pyramid aliases buf 1
    int b = blockIdx.x, t = threadIdx.x;
    const float* xb = x + (size_t)b * 65536;

    // ---- foveate: 4 glimpses x 3 pyramid levels, direct to LDS ----
    if (t < 256) {
        int r = t >> 4, c = t & 15;
        #pragma unroll
        for (int j = 0; j < 4; ++j) {
            float l0 = l[(b * 4 + j) * 2 + 0];
            float l1 = l[(b * 4 + j) * 2 + 1];
            {   // level 0 (16x16)
                int sx = (int)(0.5f * ((l0 + 1.0f) * 255.0f) - 8.0f);
                int sy = (int)(0.5f * ((l1 + 1.0f) * 255.0f) - 8.0f);
                sx = min(max(sx, 0), 240);
                sy = min(max(sy, 0), 240);
                in_s[((j * 3 + 0) * 16 + r) * 20 + c] =
                    xb[(sx + r) * 256 + sy + c];
            }
            {   // level 1 (32x32 -> 2x2 mean)
                int sx = (int)(0.5f * ((l0 + 1.0f) * 255.0f) - 16.0f);
                int sy = (int)(0.5f * ((l1 + 1.0f) * 255.0f) - 16.0f);
                sx = min(max(sx, 0), 224);
                sy = min(max(sy, 0), 224);
                const float* p = xb + (sx + 2 * r) * 256 + sy + 2 * c;
                float v00 = p[0], v01 = p[1], v10 = p[256], v11 = p[257];
                in_s[((j * 3 + 1) * 16 + r) * 20 + c] =
                    ((v00 + v01) + (v10 + v11)) * 0.25f;
            }
            {   // level 2 (64x64 -> 4x4 mean)
                int sx = (int)(0.5f * ((l0 + 1.0f) * 255.0f) - 32.0f);
                int sy = (int)(0.5f * ((l1 + 1.0f) * 255.0f) - 32.0f);
                sx = min(max(sx, 0), 192);
                sy = min(max(sy, 0), 192);
                const float* p = xb + (sx + 4 * r) * 256 + sy + 4 * c;
                float v[16];
                #pragma unroll
                for (int dy = 0; dy < 4; ++dy)
                    #pragma unroll
                    for (int dx = 0; dx < 4; ++dx)
                        v[dy * 4 + dx] = p[dy * 256 + dx];
                float s0 = (v[0]  + v[1])  + (v[2]  + v[3]);
                float s1 = (v[4]  + v[5])  + (v[6]  + v[7]);
                float s2 = (v[8]  + v[9])  + (v[10] + v[11]);
                float s3 = (v[12] + v[13]) + (v[14] + v[15]);
                in_s[((j * 3 + 2) * 16 + r) * 20 + c] =
                    ((s0 + s1) + (s2 + s3)) * 0.0625f;
            }
        }
    }
    if (t < 12) {
        int j = t / 3, i = t % 3;
        int gh = 16 << i, half = gh >> 1;
        float l0 = l[(b * 4 + j) * 2 + 0];
        float l1 = l[(b * 4 + j) * 2 + 1];
        int sx = (int)(0.5f * ((l0 + 1.0f) * 255.0f) - (float)half);
        int sy = (int)(0.5f * ((l1 + 1.0f) * 255.0f) - (float)half);
        sx = min(max(sx, 0), 256 - gh);
        sy = min(max(sy, 0), 256 - gh);
        float4 bbv = make_float4((float)sy, (float)sx,
                                 (float)(sy + gh), (float)(sx + gh));
        *(float4*)(bbox + ((size_t)b * 12 + t) * 4) = bbv;
    }
    __syncthreads();

    // ---- conv1 (threads 0..223) || stage conv2 chunk 0 (threads 256..319)
    if (t < 224) {
        int py = t >> 5, oc = t & 31;
        float a[7] = {0.f,0.f,0.f,0.f,0.f,0.f,0.f};
        for (int ch = 0; ch < 12; ++ch) {
            #pragma unroll
            for (int ky = 0; ky < 4; ++ky) {
                const float* rp = in_s + (ch * 16 + 2 * py + ky) * 20;
                float4 r0 = *(const float4*)(rp);
                float4 r1 = *(const float4*)(rp + 4);
                float4 r2 = *(const float4*)(rp + 8);
                float4 r3 = *(const float4*)(rp + 12);
                float row[16] = {r0.x,r0.y,r0.z,r0.w, r1.x,r1.y,r1.z,r1.w,
                                 r2.x,r2.y,r2.z,r2.w, r3.x,r3.y,r3.z,r3.w};
                const float* wp = w1t + (ch * 4 + ky) * 128 + oc;
                float w0 = wp[0], w1 = wp[32], w2 = wp[64], w3 = wp[96];
                #pragma unroll
                for (int px = 0; px < 7; ++px) {
                    int s2 = 2 * px;
                    a[px] += row[s2]*w0 + row[s2+1]*w1
                           + row[s2+2]*w2 + row[s2+3]*w3;
                }
            }
        }
        float bv = c1b[oc];
        #pragma unroll
        for (int px = 0; px < 7; ++px)
            h1_s[oc * 56 + py * 8 + px] = fmaxf(a[px] + bv, 0.0f);
    } else if (t >= 256) {
        // stage chunk 0 -> w2s[0] (disjoint from in_s = w2s[1])
        const float4* src = (const float4*)w2t;
        float4* dst = (float4*)w2s[0];
        for (int i = t - 256; i < 1152; i += 64) dst[i] = src[i];
    }
    __syncthreads();

    // ---- conv2: single pass, t = py*64 + oc (exactly 320 items) ----
    // weights from LDS, double-buffered in 8-channel chunks
    int py = t >> 6, oc = t & 63;
    float a[5] = {0.f,0.f,0.f,0.f,0.f};
    for (int cc = 0; cc < 4; ++cc) {
        if (cc < 3) {   // prefetch next chunk into the other buffer
            const float4* src = (const float4*)(w2t + (cc + 1) * 4608);
            float4* dst = (float4*)w2s[(cc + 1) & 1];
            for (int i = t; i < 1152; i += 320) dst[i] = src[i];
        }
        const float* wb = w2s[cc & 1];
        for (int ch8 = 0; ch8 < 8; ++ch8) {
            int ch = cc * 8 + ch8;
            #pragma unroll
            for (int ky = 0; ky < 3; ++ky) {
                const float* rp = h1_s + ch * 56 + (py + ky) * 8;  // broadcast
                float4 q0 = *(const float4*)(rp);
                float4 q1 = *(const float4*)(rp + 4);
                float row[8] = {q0.x,q0.y,q0.z,q0.w, q1.x,q1.y,q1.z,q1.w};
                #pragma unroll
                for (int kx = 0; kx < 3; ++kx) {
                    float wv = wb[(ch8 * 9 + ky * 3 + kx) * 64 + oc];
                    #pragma unroll
                    for (int px = 0; px < 5; ++px)
                        a[px] += row[px + kx] * wv;
                }
            }
        }
        __syncthreads();
    }
    float bv = c2b[oc];
    float* o = h2 + (size_t)b * 1600 + oc * 25 + py * 5;
    #pragma unroll
    for (int px = 0; px < 5; ++px)
        o[px] = fmaxf(a[px] + bv, 0.0f);
}

// ---- Kernel 2: fc1 partial GEMM, 8 k-chunks of 200 ------------------------
__global__ __launch_bounds__(256) void fc1_partial_kernel(
    const float* __restrict__ h2,      // [512,1600]
    const float* __restrict__ w,       // [256,1600]
    float* __restrict__ partial)       // [8,512,256]
{
    int bt = blockIdx.x, kc = blockIdx.y, t = threadIdx.x;
    const float4* wp = (const float4*)(w + (size_t)t * 1600 + kc * 200);
    const float*  hb = h2 + (size_t)bt * 8 * 1600 + kc * 200;
    float acc[8] = {0.f,0.f,0.f,0.f,0.f,0.f,0.f,0.f};
    for (int k4 = 0; k4 < 50; ++k4) {
        float4 wv = wp[k4];
        #pragma unroll
        for (int bb = 0; bb < 8; ++bb) {
            float4 iv = *(const float4*)(hb + bb * 1600 + k4 * 4);
            acc[bb] += wv.x*iv.x + wv.y*iv.y + wv.z*iv.z + wv.w*iv.w;
        }
    }
    float* pp = partial + ((size_t)kc * 512 + bt * 8) * 256 + t;
    #pragma unroll
    for (int bb = 0; bb < 8; ++bb) pp[bb * 256] = acc[bb];
}

// ---- Kernel 3: fc_tail = fc1-reduce+ReLU -> phi_out; fc2; fc3/fc4 -> g_t --
__global__ __launch_bounds__(384) void fc_tail_kernel(
    const float* __restrict__ partial,  // [8,512,256]
    const float* __restrict__ fc1_b,    // [256]
    const float* __restrict__ l,        // [512,8]
    const float* __restrict__ fc2_w,    // [128,8]
    const float* __restrict__ fc2_b,    // [128]
    const float* __restrict__ w3t,      // [64,384,4] repacked fc3_w
    const float* __restrict__ fc3_b,    // [384]
    const float* __restrict__ w4t,      // [32,384,4] repacked fc4_w
    const float* __restrict__ fc4_b,    // [384]
    float* __restrict__ phi_out,        // [512,256]
    float* __restrict__ g_t)            // [512,384]
{
    __shared__ __align__(16) float ph_s[2 * 256];
    __shared__ __align__(16) float lo_s[2 * 128];
    int bt = blockIdx.x, t = threadIdx.x;

    for (int idx = t; idx < 512; idx += 384) {
        int bb = idx >> 8, ch = idx & 255;
        size_t gidx = ((size_t)(bt * 2 + bb)) * 256 + ch;
        float s = fc1_b[ch];
        #pragma unroll
        for (int kc = 0; kc < 8; ++kc) s += partial[(size_t)kc * 131072 + gidx];
        s = fmaxf(s, 0.0f);
        ph_s[idx] = s;
        phi_out[gidx] = s;
    }
    for (int idx = t; idx < 256; idx += 384) {
        int bb = idx >> 7, ch = idx & 127;
        int b = bt * 2 + bb;
        float a = fc2_b[ch];
        const float* lb = l + b * 8;
        const float* wr = fc2_w + ch * 8;
        #pragma unroll
        for (int m = 0; m < 8; ++m) a += lb[m] * wr[m];
        lo_s[idx] = fmaxf(a, 0.0f);
    }
    __syncthreads();

    float base = fc3_b[t] + fc4_b[t];
    float acc0 = base, acc1 = base;
    const float4* w3p = (const float4*)w3t + t;       // [k4][384 lanes]
    #pragma unroll 8
    for (int k4 = 0; k4 < 64; ++k4) {
        float4 wv = w3p[(size_t)k4 * 384];            // lane-coalesced
        float4 a0 = *(const float4*)&ph_s[k4 * 4];    // broadcast
        float4 a1 = *(const float4*)&ph_s[256 + k4 * 4];
        acc0 += wv.x*a0.x + wv.y*a0.y + wv.z*a0.z + wv.w*a0.w;
        acc1 += wv.x*a1.x + wv.y*a1.y + wv.z*a1.z + wv.w*a1.w;
    }
    const float4* w4p = (const float4*)w4t + t;
    #pragma unroll 8
    for (int k4 = 0; k4 < 32; ++k4) {
        float4 wv = w4p[(size_t)k4 * 384];
        float4 a0 = *(const float4*)&lo_s[k4 * 4];
        float4 a1 = *(const float4*)&lo_s[128 + k4 * 4];
        acc0 += wv.x*a0.x + wv.y*a0.y + wv.z*a0.z + wv.w*a0.w;
        acc1 += wv.x*a1.x + wv.y*a1.y + wv.z*a1.z + wv.w*a1.w;
    }
    g_t[((size_t)bt * 2 + 0) * 384 + t] = fmaxf(acc0, 0.0f);
    g_t[((size_t)bt * 2 + 1) * 384 + t] = fmaxf(acc1, 0.0f);
}

extern "C" void kernel_launch(void* const* d_in, const int* in_sizes, int n_in,
                              void* d_out, int out_size, void* d_ws, size_t ws_size,
                              hipStream_t stream) {
    const float* x   = (const float*)d_in[0];
    const float* l   = (const float*)d_in[1];
    const float* c1w = (const float*)d_in[2];
    const float* c1b = (const float*)d_in[3];
    const float* c2w = (const float*)d_in[4];
    const float* c2b = (const float*)d_in[5];
    const float* f1w = (const float*)d_in[6];
    const float* f1b = (const float*)d_in[7];
    const float* f2w = (const float*)d_in[8];
    const float* f2b = (const float*)d_in[9];
    const float* f3w = (const float*)d_in[10];
    const float* f3b = (const float*)d_in[11];
    const float* f4w = (const float*)d_in[12];
    const float* f4b = (const float*)d_in[13];

    float* out       = (float*)d_out;
    float* phi_out_p = out + PHI_OUT_OFF;
    float* gt_p      = out + GT_OFF;
    float* bbox_p    = out + BBOX_OFF;

    float* ws      = (float*)d_ws;
    float* h2      = ws + WS_H2;
    float* partial = ws + WS_PART;
    float* w2t     = ws + WS_W2T;
    float* w1t     = ws + WS_W1T;
    float* w3t     = ws + WS_W3T;
    float* w4t     = ws + WS_W4T;

    repack_kernel<<<672, 256, 0, stream>>>(c2w, c1w, f3w, f4w,
                                           w2t, w1t, w3t, w4t);
    glimpse_conv_kernel<<<512, 320, 0, stream>>>(x, l, w1t, c1b, w2t, c2b,
                                                 h2, bbox_p);
    fc1_partial_kernel<<<dim3(64, 8), 256, 0, stream>>>(h2, f1w, partial);
    fc_tail_kernel<<<256, 384, 0, stream>>>(partial, f1b, l, f2w, f2b,
                                            w3t, f3b, w4t, f4b,
                                            phi_out_p, gt_p);
}

// Round 2
// 78.516 us; speedup vs baseline: 1.1410x; 1.1410x over previous
//
#include <hip/hip_runtime.h>

// ---------------------------------------------------------------------------
// GlimpseNetwork forward, fp32. Round 10: round-8 structure, plus
//  * glimpse_conv: 320-thread blocks, single-pass conv2 (t -> (py,oc), exactly
//    320 items, no half-idle second pass). conv2 weights read from GLOBAL
//    (coalesced 256B wave loads, L2-resident) -- the round-9 LDS
//    double-buffer staging was pure overhead and is reverted.
//  * fc3/fc4 weights repacked to [k4][384][4] -> lane-coalesced streaming
//    reads in fc_tail (kept from round 9).
// Pipeline:
//   repack (672 blk) : c2w->w2t[r][64oc]; c1w->w1t; f3w->w3t; f4w->w4t
//   glimpse_conv(512x320): foveate->in_s(LDS), conv1->h1_s, conv2->h2, bbox
//   fc1_partial(64x8): K-split GEMM -> partial
//   fc_tail (256)    : reduce+ReLU->phi_out, fc2, fc3/fc4 -> g_t
//
// d_out layout (floats): phi_out[512*256] | g_t[512*384] | bboxes[512*12*4]
// ws (floats): h2[0,819200) part[819200,1867776) w2t[1867776,1886208)
//              w1t[1886208,1892352) w3t[1892352,1990656) w4t[1990656,2039808)
// ---------------------------------------------------------------------------

#define PHI_OUT_OFF 0
#define GT_OFF      131072
#define BBOX_OFF    327680

#define WS_H2    0
#define WS_PART  819200
#define WS_W2T   1867776
#define WS_W1T   1886208
#define WS_W3T   1892352
#define WS_W4T   1990656

// ---- Kernel 0: weight repacks --------------------------------------------
__global__ __launch_bounds__(256) void repack_kernel(
    const float* __restrict__ c2w,   // [64,32,3,3]
    const float* __restrict__ c1w,   // [32,12,4,4]
    const float* __restrict__ f3w,   // [384,256]
    const float* __restrict__ f4w,   // [384,128]
    float* __restrict__ w2t,         // [288,64]
    float* __restrict__ w1t,         // [48,4,32]
    float* __restrict__ w3t,         // [64,384,4]
    float* __restrict__ w4t)         // [32,384,4]
{
    int idx = blockIdx.x * 256 + threadIdx.x;
    if (idx < 18432) {                         // conv2: [oc][r] -> [r][64oc]
        int oc = idx / 288, r = idx % 288;
        w2t[r * 64 + oc] = c2w[idx];
    } else if (idx < 24576) {                  // conv1 -> [(ch*4+ky)][kx][32oc]
        int g1 = idx - 18432;
        int oc = g1 / 192, rem = g1 % 192;
        int ch = rem / 16, kk = rem % 16, ky = kk / 4, kx = kk % 4;
        w1t[(ch * 4 + ky) * 128 + kx * 32 + oc] = c1w[g1];
    } else if (idx < 122880) {                 // fc3: [ch][k] -> [k4][384ch][4]
        int i = idx - 24576;
        int ch = i >> 8, k = i & 255;
        w3t[((k >> 2) * 384 + ch) * 4 + (k & 3)] = f3w[i];
    } else if (idx < 172032) {                 // fc4: [ch][k] -> [k4][384ch][4]
        int i = idx - 122880;
        int ch = i >> 7, k = i & 127;
        w4t[((k >> 2) * 384 + ch) * 4 + (k & 3)] = f4w[i];
    }
}

// ---- Kernel 1: fused foveate + conv1 + conv2, one block per image ---------
// 512 blocks, 320 threads. LDS: in_s 15.4 KB + h1_s 7.2 KB = 22.6 KB.
__global__ __launch_bounds__(320) void glimpse_conv_kernel(
    const float* __restrict__ x,     // [512,1,256,256]
    const float* __restrict__ l,     // [512,4,2]
    const float* __restrict__ w1t,   // [48,4,32]
    const float* __restrict__ c1b,   // [32]
    const float* __restrict__ w2t,   // [288,64]
    const float* __restrict__ c2b,   // [64]
    float* __restrict__ h2,          // [512,1600]
    float* __restrict__ bbox)        // [512,12,4]
{
    __shared__ __align__(16) float in_s[12 * 16 * 20];  // rows padded ->20
    __shared__ __align__(16) float h1_s[32 * 7 * 8];    // rows padded ->8
    int b = blockIdx.x, t = threadIdx.x;
    const float* xb = x + (size_t)b * 65536;

    // ---- foveate: 4 glimpses x 3 pyramid levels, direct to LDS ----
    if (t < 256) {
        int r = t >> 4, c = t & 15;
        #pragma unroll
        for (int j = 0; j < 4; ++j) {
            float l0 = l[(b * 4 + j) * 2 + 0];
            float l1 = l[(b * 4 + j) * 2 + 1];
            {   // level 0 (16x16)
                int sx = (int)(0.5f * ((l0 + 1.0f) * 255.0f) - 8.0f);
                int sy = (int)(0.5f * ((l1 + 1.0f) * 255.0f) - 8.0f);
                sx = min(max(sx, 0), 240);
                sy = min(max(sy, 0), 240);
                in_s[((j * 3 + 0) * 16 + r) * 20 + c] =
                    xb[(sx + r) * 256 + sy + c];
            }
            {   // level 1 (32x32 -> 2x2 mean)
                int sx = (int)(0.5f * ((l0 + 1.0f) * 255.0f) - 16.0f);
                int sy = (int)(0.5f * ((l1 + 1.0f) * 255.0f) - 16.0f);
                sx = min(max(sx, 0), 224);
                sy = min(max(sy, 0), 224);
                const float* p = xb + (sx + 2 * r) * 256 + sy + 2 * c;
                float v00 = p[0], v01 = p[1], v10 = p[256], v11 = p[257];
                in_s[((j * 3 + 1) * 16 + r) * 20 + c] =
                    ((v00 + v01) + (v10 + v11)) * 0.25f;
            }
            {   // level 2 (64x64 -> 4x4 mean)
                int sx = (int)(0.5f * ((l0 + 1.0f) * 255.0f) - 32.0f);
                int sy = (int)(0.5f * ((l1 + 1.0f) * 255.0f) - 32.0f);
                sx = min(max(sx, 0), 192);
                sy = min(max(sy, 0), 192);
                const float* p = xb + (sx + 4 * r) * 256 + sy + 4 * c;
                float v[16];
                #pragma unroll
                for (int dy = 0; dy < 4; ++dy)
                    #pragma unroll
                    for (int dx = 0; dx < 4; ++dx)
                        v[dy * 4 + dx] = p[dy * 256 + dx];
                float s0 = (v[0]  + v[1])  + (v[2]  + v[3]);
                float s1 = (v[4]  + v[5])  + (v[6]  + v[7]);
                float s2 = (v[8]  + v[9])  + (v[10] + v[11]);
                float s3 = (v[12] + v[13]) + (v[14] + v[15]);
                in_s[((j * 3 + 2) * 16 + r) * 20 + c] =
                    ((s0 + s1) + (s2 + s3)) * 0.0625f;
            }
        }
    }
    if (t < 12) {
        int j = t / 3, i = t % 3;
        int gh = 16 << i, half = gh >> 1;
        float l0 = l[(b * 4 + j) * 2 + 0];
        float l1 = l[(b * 4 + j) * 2 + 1];
        int sx = (int)(0.5f * ((l0 + 1.0f) * 255.0f) - (float)half);
        int sy = (int)(0.5f * ((l1 + 1.0f) * 255.0f) - (float)half);
        sx = min(max(sx, 0), 256 - gh);
        sy = min(max(sy, 0), 256 - gh);
        float4 bbv = make_float4((float)sy, (float)sx,
                                 (float)(sy + gh), (float)(sx + gh));
        *(float4*)(bbox + ((size_t)b * 12 + t) * 4) = bbv;
    }
    __syncthreads();

    // ---- conv1: t = py*32 + oc, 224 active; coalesced w1t reads ----
    if (t < 224) {
        int py = t >> 5, oc = t & 31;
        float a[7] = {0.f,0.f,0.f,0.f,0.f,0.f,0.f};
        for (int ch = 0; ch < 12; ++ch) {
            #pragma unroll
            for (int ky = 0; ky < 4; ++ky) {
                const float* rp = in_s + (ch * 16 + 2 * py + ky) * 20;
                float4 r0 = *(const float4*)(rp);
                float4 r1 = *(const float4*)(rp + 4);
                float4 r2 = *(const float4*)(rp + 8);
                float4 r3 = *(const float4*)(rp + 12);
                float row[16] = {r0.x,r0.y,r0.z,r0.w, r1.x,r1.y,r1.z,r1.w,
                                 r2.x,r2.y,r2.z,r2.w, r3.x,r3.y,r3.z,r3.w};
                const float* wp = w1t + (ch * 4 + ky) * 128 + oc;
                float w0 = wp[0], w1 = wp[32], w2 = wp[64], w3 = wp[96];
                #pragma unroll
                for (int px = 0; px < 7; ++px) {
                    int s2 = 2 * px;
                    a[px] += row[s2]*w0 + row[s2+1]*w1
                           + row[s2+2]*w2 + row[s2+3]*w3;
                }
            }
        }
        float bv = c1b[oc];
        #pragma unroll
        for (int px = 0; px < 7; ++px)
            h1_s[oc * 56 + py * 8 + px] = fmaxf(a[px] + bv, 0.0f);
    }
    __syncthreads();

    // ---- conv2: single pass, t = (py = t>>6, oc = t&63), 320 items ----
    // weights from global: lanes read 64 consecutive floats (256B, L2-hit)
    int py = t >> 6, oc = t & 63;
    float a[5] = {0.f,0.f,0.f,0.f,0.f};
    for (int ch = 0; ch < 32; ++ch) {
        #pragma unroll
        for (int ky = 0; ky < 3; ++ky) {
            const float* rp = h1_s + ch * 56 + (py + ky) * 8;  // broadcast
            float4 q0 = *(const float4*)(rp);
            float4 q1 = *(const float4*)(rp + 4);
            float row[8] = {q0.x,q0.y,q0.z,q0.w, q1.x,q1.y,q1.z,q1.w};
            #pragma unroll
            for (int kx = 0; kx < 3; ++kx) {
                float wv = w2t[(ch * 9 + ky * 3 + kx) * 64 + oc];  // coalesced
                #pragma unroll
                for (int px = 0; px < 5; ++px)
                    a[px] += row[px + kx] * wv;
            }
        }
    }
    float bv = c2b[oc];
    float* o = h2 + (size_t)b * 1600 + oc * 25 + py * 5;
    #pragma unroll
    for (int px = 0; px < 5; ++px)
        o[px] = fmaxf(a[px] + bv, 0.0f);
}

// ---- Kernel 2: fc1 partial GEMM, 8 k-chunks of 200 ------------------------
__global__ __launch_bounds__(256) void fc1_partial_kernel(
    const float* __restrict__ h2,      // [512,1600]
    const float* __restrict__ w,       // [256,1600]
    float* __restrict__ partial)       // [8,512,256]
{
    int bt = blockIdx.x, kc = blockIdx.y, t = threadIdx.x;
    const float4* wp = (const float4*)(w + (size_t)t * 1600 + kc * 200);
    const float*  hb = h2 + (size_t)bt * 8 * 1600 + kc * 200;
    float acc[8] = {0.f,0.f,0.f,0.f,0.f,0.f,0.f,0.f};
    for (int k4 = 0; k4 < 50; ++k4) {
        float4 wv = wp[k4];
        #pragma unroll
        for (int bb = 0; bb < 8; ++bb) {
            float4 iv = *(const float4*)(hb + bb * 1600 + k4 * 4);
            acc[bb] += wv.x*iv.x + wv.y*iv.y + wv.z*iv.z + wv.w*iv.w;
        }
    }
    float* pp = partial + ((size_t)kc * 512 + bt * 8) * 256 + t;
    #pragma unroll
    for (int bb = 0; bb < 8; ++bb) pp[bb * 256] = acc[bb];
}

// ---- Kernel 3: fc_tail = fc1-reduce+ReLU -> phi_out; fc2; fc3/fc4 -> g_t --
__global__ __launch_bounds__(384) void fc_tail_kernel(
    const float* __restrict__ partial,  // [8,512,256]
    const float* __restrict__ fc1_b,    // [256]
    const float* __restrict__ l,        // [512,8]
    const float* __restrict__ fc2_w,    // [128,8]
    const float* __restrict__ fc2_b,    // [128]
    const float* __restrict__ w3t,      // [64,384,4] repacked fc3_w
    const float* __restrict__ fc3_b,    // [384]
    const float* __restrict__ w4t,      // [32,384,4] repacked fc4_w
    const float* __restrict__ fc4_b,    // [384]
    float* __restrict__ phi_out,        // [512,256]
    float* __restrict__ g_t)            // [512,384]
{
    __shared__ __align__(16) float ph_s[2 * 256];
    __shared__ __align__(16) float lo_s[2 * 128];
    int bt = blockIdx.x, t = threadIdx.x;

    for (int idx = t; idx < 512; idx += 384) {
        int bb = idx >> 8, ch = idx & 255;
        size_t gidx = ((size_t)(bt * 2 + bb)) * 256 + ch;
        float s = fc1_b[ch];
        #pragma unroll
        for (int kc = 0; kc < 8; ++kc) s += partial[(size_t)kc * 131072 + gidx];
        s = fmaxf(s, 0.0f);
        ph_s[idx] = s;
        phi_out[gidx] = s;
    }
    for (int idx = t; idx < 256; idx += 384) {
        int bb = idx >> 7, ch = idx & 127;
        int b = bt * 2 + bb;
        float a = fc2_b[ch];
        const float* lb = l + b * 8;
        const float* wr = fc2_w + ch * 8;
        #pragma unroll
        for (int m = 0; m < 8; ++m) a += lb[m] * wr[m];
        lo_s[idx] = fmaxf(a, 0.0f);
    }
    __syncthreads();

    float base = fc3_b[t] + fc4_b[t];
    float acc0 = base, acc1 = base;
    const float4* w3p = (const float4*)w3t + t;       // [k4][384 lanes]
    #pragma unroll 8
    for (int k4 = 0; k4 < 64; ++k4) {
        float4 wv = w3p[(size_t)k4 * 384];            // lane-coalesced
        float4 a0 = *(const float4*)&ph_s[k4 * 4];    // broadcast
        float4 a1 = *(const float4*)&ph_s[256 + k4 * 4];
        acc0 += wv.x*a0.x + wv.y*a0.y + wv.z*a0.z + wv.w*a0.w;
        acc1 += wv.x*a1.x + wv.y*a1.y + wv.z*a1.z + wv.w*a1.w;
    }
    const float4* w4p = (const float4*)w4t + t;
    #pragma unroll 8
    for (int k4 = 0; k4 < 32; ++k4) {
        float4 wv = w4p[(size_t)k4 * 384];
        float4 a0 = *(const float4*)&lo_s[k4 * 4];
        float4 a1 = *(const float4*)&lo_s[128 + k4 * 4];
        acc0 += wv.x*a0.x + wv.y*a0.y + wv.z*a0.z + wv.w*a0.w;
        acc1 += wv.x*a1.x + wv.y*a1.y + wv.z*a1.z + wv.w*a1.w;
    }
    g_t[((size_t)bt * 2 + 0) * 384 + t] = fmaxf(acc0, 0.0f);
    g_t[((size_t)bt * 2 + 1) * 384 + t] = fmaxf(acc1, 0.0f);
}

extern "C" void kernel_launch(void* const* d_in, const int* in_sizes, int n_in,
                              void* d_out, int out_size, void* d_ws, size_t ws_size,
                              hipStream_t stream) {
    const float* x   = (const float*)d_in[0];
    const float* l   = (const float*)d_in[1];
    const float* c1w = (const float*)d_in[2];
    const float* c1b = (const float*)d_in[3];
    const float* c2w = (const float*)d_in[4];
    const float* c2b = (const float*)d_in[5];
    const float* f1w = (const float*)d_in[6];
    const float* f1b = (const float*)d_in[7];
    const float* f2w = (const float*)d_in[8];
    const float* f2b = (const float*)d_in[9];
    const float* f3w = (const float*)d_in[10];
    const float* f3b = (const float*)d_in[11];
    const float* f4w = (const float*)d_in[12];
    const float* f4b = (const float*)d_in[13];

    float* out       = (float*)d_out;
    float* phi_out_p = out + PHI_OUT_OFF;
    float* gt_p      = out + GT_OFF;
    float* bbox_p    = out + BBOX_OFF;

    float* ws      = (float*)d_ws;
    float* h2      = ws + WS_H2;
    float* partial = ws + WS_PART;
    float* w2t     = ws + WS_W2T;
    float* w1t     = ws + WS_W1T;
    float* w3t     = ws + WS_W3T;
    float* w4t     = ws + WS_W4T;

    repack_kernel<<<672, 256, 0, stream>>>(c2w, c1w, f3w, f4w,
                                           w2t, w1t, w3t, w4t);
    glimpse_conv_kernel<<<512, 320, 0, stream>>>(x, l, w1t, c1b, w2t, c2b,
                                                 h2, bbox_p);
    fc1_partial_kernel<<<dim3(64, 8), 256, 0, stream>>>(h2, f1w, partial);
    fc_tail_kernel<<<256, 384, 0, stream>>>(partial, f1b, l, f2w, f2b,
                                            w3t, f3b, w4t, f4b,
                                            phi_out_p, gt_p);
}